// Round 1
// baseline (3179.519 us; speedup 1.0000x reference)
//
#include <hip/hip_runtime.h>
#include <stdint.h>

#define TT 4096   // B*S tokens
#define DD 1024   // model dim
#define EE 8      // experts
#define HH 1792   // hidden dim

typedef __attribute__((ext_vector_type(8))) short short8;   // 8 x bf16 frag
typedef __attribute__((ext_vector_type(4))) float f32x4;

static __device__ __forceinline__ unsigned short f2bf(float f) {
  union { float f; uint32_t u; } v; v.f = f;
  return (unsigned short)((v.u + 0x7fffu + ((v.u >> 16) & 1u)) >> 16);  // RNE
}
static __device__ __forceinline__ float bf2f(unsigned short h) {
  union { uint32_t u; float f; } v; v.u = ((uint32_t)h) << 16;
  return v.f;
}

// ---------------- gate: logits (bf16-emulated), top-2, combine, probs ----------------
__global__ __launch_bounds__(256) void gate_kernel(
    const float* __restrict__ x, const float* __restrict__ gw,
    float* __restrict__ combine, float* __restrict__ probs) {
  const int lane = threadIdx.x & 63;
  const int wave = threadIdx.x >> 6;
  const int t = blockIdx.x * 4 + wave;
  const float* xr = x + (size_t)t * DD;
  float acc[EE];
#pragma unroll
  for (int e = 0; e < EE; ++e) acc[e] = 0.f;
  for (int i = 0; i < DD / 64; ++i) {
    const int d = i * 64 + lane;
    const float xv = bf2f(f2bf(xr[d]));
#pragma unroll
    for (int e = 0; e < EE; ++e)
      acc[e] += xv * bf2f(f2bf(gw[e * DD + d]));
  }
#pragma unroll
  for (int e = 0; e < EE; ++e) {
#pragma unroll
    for (int off = 32; off > 0; off >>= 1)
      acc[e] += __shfl_xor(acc[e], off, 64);
  }
  if (lane == 0) {
    float lg[EE];
#pragma unroll
    for (int e = 0; e < EE; ++e) lg[e] = bf2f(f2bf(acc[e]));  // ref rounds matmul out to bf16
    float m1 = -1e30f, m2 = -1e30f; int i1 = 0, i2 = 0;
#pragma unroll
    for (int e = 0; e < EE; ++e) {
      const float v = lg[e];
      if (v > m1) { m2 = m1; i2 = i1; m1 = v; i1 = e; }
      else if (v > m2) { m2 = v; i2 = e; }
    }
    const float e2 = expf(m2 - m1);
    const float w1 = 1.f / (1.f + e2);
    const float w2 = e2 * w1;
    float cb[EE];
#pragma unroll
    for (int e = 0; e < EE; ++e) cb[e] = 0.f;
    cb[i1] = w1; cb[i2] += w2;
    float p[EE]; float s = 0.f;
#pragma unroll
    for (int e = 0; e < EE; ++e) { p[e] = expf(lg[e] - m1); s += p[e]; }
    const float inv = 1.f / s;
#pragma unroll
    for (int e = 0; e < EE; ++e) {
      combine[(size_t)t * EE + e] = cb[e];
      probs[(size_t)t * EE + e] = p[e] * inv;
    }
  }
}

// ---------------- deterministic probs reduction -> mean_probs + loss ----------------
__global__ __launch_bounds__(256) void reduce_kernel(
    const float* __restrict__ probs, float* __restrict__ tail) {
  const int tid = threadIdx.x;
  const int lane = tid & 63, wave = tid >> 6;
  float acc[EE];
#pragma unroll
  for (int e = 0; e < EE; ++e) acc[e] = 0.f;
  for (int t = tid; t < TT; t += 256) {
#pragma unroll
    for (int e = 0; e < EE; ++e) acc[e] += probs[(size_t)t * EE + e];
  }
#pragma unroll
  for (int e = 0; e < EE; ++e) {
#pragma unroll
    for (int off = 32; off > 0; off >>= 1)
      acc[e] += __shfl_xor(acc[e], off, 64);
  }
  __shared__ float sm[4][EE];
  if (lane == 0) {
#pragma unroll
    for (int e = 0; e < EE; ++e) sm[wave][e] = acc[e];
  }
  __syncthreads();
  if (tid == 0) {
    float loss = 0.f;
#pragma unroll
    for (int e = 0; e < EE; ++e) {
      const float m = (sm[0][e] + sm[1][e] + sm[2][e] + sm[3][e]) * (1.f / TT);
      tail[1 + e] = m;
      loss += m * m;
    }
    tail[0] = (float)EE * loss;
  }
}

// ---------------- fused gate+up GEMM: act = bf16(silu(X@Wg) * (X@Wu)) ----------------
__global__ void gemm_gu(const float* __restrict__ X, const float* __restrict__ Wg,
                        const float* __restrict__ Wu, unsigned short* __restrict__ A) {
  __shared__ unsigned short As[128][40];
  __shared__ unsigned short Bgs[128][40];
  __shared__ unsigned short Bus[128][40];
  const int tid = threadIdx.x;
  const int lane = tid & 63, wave = tid >> 6;
  const int wm = (wave >> 1) * 64, wn = (wave & 1) * 64;
  const size_t bm0 = (size_t)blockIdx.x * 128;
  const size_t bn0 = (size_t)blockIdx.y * 128;

  f32x4 accG[4][4], accU[4][4];
#pragma unroll
  for (int i = 0; i < 4; ++i)
#pragma unroll
    for (int j = 0; j < 4; ++j) {
      accG[i][j] = (f32x4){0.f, 0.f, 0.f, 0.f};
      accU[i][j] = (f32x4){0.f, 0.f, 0.f, 0.f};
    }

  const int am = tid >> 1, ak = (tid & 1) * 16;     // A staging: row, k-half
  const int bn = tid & 127, bk = (tid >> 7) * 16;   // B staging: col, k-half
  const int fr = lane & 15, k8 = (lane >> 4) * 8;   // frag row/col, frag k

  for (int k0 = 0; k0 < DD; k0 += 32) {
    {  // A tile: [128 tokens][32 k] f32 -> bf16
      const float* src = X + (bm0 + am) * DD + k0 + ak;
      union { unsigned short s[16]; short8 v[2]; } pk;
#pragma unroll
      for (int q = 0; q < 4; ++q) {
        const f32x4 t = *(const f32x4*)(src + 4 * q);
        pk.s[4 * q + 0] = f2bf(t[0]); pk.s[4 * q + 1] = f2bf(t[1]);
        pk.s[4 * q + 2] = f2bf(t[2]); pk.s[4 * q + 3] = f2bf(t[3]);
      }
      *(short8*)&As[am][ak] = pk.v[0];
      *(short8*)&As[am][ak + 8] = pk.v[1];
    }
    {  // B tiles (stored [n][k] for contiguous frag reads), column gather
      const float* g = Wg + (size_t)(k0 + bk) * HH + bn0 + bn;
      const float* u = Wu + (size_t)(k0 + bk) * HH + bn0 + bn;
      union { unsigned short s[16]; short8 v[2]; } pg, pu;
#pragma unroll
      for (int kk = 0; kk < 16; ++kk) {
        pg.s[kk] = f2bf(g[(size_t)kk * HH]);
        pu.s[kk] = f2bf(u[(size_t)kk * HH]);
      }
      *(short8*)&Bgs[bn][bk] = pg.v[0];
      *(short8*)&Bgs[bn][bk + 8] = pg.v[1];
      *(short8*)&Bus[bn][bk] = pu.v[0];
      *(short8*)&Bus[bn][bk + 8] = pu.v[1];
    }
    __syncthreads();
    short8 a[4], bg[4], bu[4];
#pragma unroll
    for (int i = 0; i < 4; ++i) a[i] = *(const short8*)&As[wm + i * 16 + fr][k8];
#pragma unroll
    for (int j = 0; j < 4; ++j) {
      bg[j] = *(const short8*)&Bgs[wn + j * 16 + fr][k8];
      bu[j] = *(const short8*)&Bus[wn + j * 16 + fr][k8];
    }
#pragma unroll
    for (int i = 0; i < 4; ++i)
#pragma unroll
      for (int j = 0; j < 4; ++j) {
        accG[i][j] = __builtin_amdgcn_mfma_f32_16x16x32_bf16(a[i], bg[j], accG[i][j], 0, 0, 0);
        accU[i][j] = __builtin_amdgcn_mfma_f32_16x16x32_bf16(a[i], bu[j], accU[i][j], 0, 0, 0);
      }
    __syncthreads();
  }
  const int r4 = (lane >> 4) * 4;
#pragma unroll
  for (int i = 0; i < 4; ++i)
#pragma unroll
    for (int j = 0; j < 4; ++j)
#pragma unroll
      for (int r = 0; r < 4; ++r) {
        const size_t row = bm0 + wm + i * 16 + r4 + r;
        const size_t col = bn0 + wn + j * 16 + fr;
        const float gg = accG[i][j][r], uu = accU[i][j][r];
        const float sv = gg / (1.f + expf(-gg));  // silu in f32
        A[row * HH + col] = f2bf(sv * uu);
      }
}

// ---------------- down GEMM + weighted accumulate into out ----------------
__global__ void gemm_down(const unsigned short* __restrict__ A, const float* __restrict__ Wd,
                          const float* __restrict__ combine, const int e, const int first,
                          float* __restrict__ out) {
  __shared__ unsigned short As[128][40];
  __shared__ unsigned short Bs[128][40];
  const int tid = threadIdx.x;
  const int lane = tid & 63, wave = tid >> 6;
  const int wm = (wave >> 1) * 64, wn = (wave & 1) * 64;
  const size_t bm0 = (size_t)blockIdx.x * 128;
  const size_t bn0 = (size_t)blockIdx.y * 128;

  f32x4 acc[4][4];
#pragma unroll
  for (int i = 0; i < 4; ++i)
#pragma unroll
    for (int j = 0; j < 4; ++j) acc[i][j] = (f32x4){0.f, 0.f, 0.f, 0.f};

  const int am = tid >> 1, ak = (tid & 1) * 16;
  const int bn = tid & 127, bk = (tid >> 7) * 16;
  const int fr = lane & 15, k8 = (lane >> 4) * 8;

  for (int k0 = 0; k0 < HH; k0 += 32) {
    {  // A tile already bf16: two 16B loads
      const unsigned short* src = A + (bm0 + am) * HH + k0 + ak;
      *(short8*)&As[am][ak] = *(const short8*)(src);
      *(short8*)&As[am][ak + 8] = *(const short8*)(src + 8);
    }
    {  // B tile from Wd (f32, ld=DD), stored [n][k]
      const float* w = Wd + (size_t)(k0 + bk) * DD + bn0 + bn;
      union { unsigned short s[16]; short8 v[2]; } pw;
#pragma unroll
      for (int kk = 0; kk < 16; ++kk) pw.s[kk] = f2bf(w[(size_t)kk * DD]);
      *(short8*)&Bs[bn][bk] = pw.v[0];
      *(short8*)&Bs[bn][bk + 8] = pw.v[1];
    }
    __syncthreads();
    short8 a[4], b[4];
#pragma unroll
    for (int i = 0; i < 4; ++i) a[i] = *(const short8*)&As[wm + i * 16 + fr][k8];
#pragma unroll
    for (int j = 0; j < 4; ++j) b[j] = *(const short8*)&Bs[wn + j * 16 + fr][k8];
#pragma unroll
    for (int i = 0; i < 4; ++i)
#pragma unroll
      for (int j = 0; j < 4; ++j)
        acc[i][j] = __builtin_amdgcn_mfma_f32_16x16x32_bf16(a[i], b[j], acc[i][j], 0, 0, 0);
    __syncthreads();
  }
  const int r4 = (lane >> 4) * 4;
#pragma unroll
  for (int i = 0; i < 4; ++i)
#pragma unroll
    for (int r = 0; r < 4; ++r) {
      const size_t row = bm0 + wm + i * 16 + r4 + r;
      const float c = combine[row * EE + e];
#pragma unroll
      for (int j = 0; j < 4; ++j) {
        const size_t col = bn0 + wn + j * 16 + fr;
        const float y = acc[i][j][r] * c;
        if (first) out[row * DD + col] = y;           // expert 0 initializes
        else if (c != 0.f) out[row * DD + col] += y;  // others RMW, skip zero rows
      }
    }
}

extern "C" void kernel_launch(void* const* d_in, const int* in_sizes, int n_in,
                              void* d_out, int out_size, void* d_ws, size_t ws_size,
                              hipStream_t stream) {
  const float* x      = (const float*)d_in[0];
  const float* gw     = (const float*)d_in[1];
  const float* w_gate = (const float*)d_in[2];
  const float* w_up   = (const float*)d_in[3];
  const float* w_down = (const float*)d_in[4];
  float* out = (float*)d_out;
  float* tail = out + (size_t)TT * DD;  // [loss, mean_probs x 8]

  float* combine = (float*)d_ws;                         // [TT][EE]
  float* probs = combine + (size_t)TT * EE;              // [TT][EE]
  unsigned short* act = (unsigned short*)(probs + (size_t)TT * EE);  // [TT][HH] bf16

  gate_kernel<<<TT / 4, 256, 0, stream>>>(x, gw, combine, probs);
  reduce_kernel<<<1, 256, 0, stream>>>(probs, tail);
  for (int e = 0; e < EE; ++e) {
    gemm_gu<<<dim3(TT / 128, HH / 128), 256, 0, stream>>>(
        x, w_gate + (size_t)e * DD * HH, w_up + (size_t)e * DD * HH, act);
    gemm_down<<<dim3(TT / 128, DD / 128), 256, 0, stream>>>(
        act, w_down + (size_t)e * HH * DD, combine, e, e == 0, out);
  }
}

// Round 2
// 374.848 us; speedup vs baseline: 8.4822x; 8.4822x over previous
//
#include <hip/hip_runtime.h>
#include <stdint.h>

#define TT 4096   // B*S tokens
#define DD 1024   // model dim
#define EE 8      // experts
#define HH 1792   // hidden dim
#define MP 10240  // max padded gathered rows (MAXT*128)
#define MAXT 80   // max row tiles: ceil((8192 + 8*127)/128) = 72, padded to 80

typedef __attribute__((ext_vector_type(8))) short short8;    // 8 x bf16
typedef __attribute__((ext_vector_type(4))) short short4v;   // 4 x bf16
typedef __attribute__((ext_vector_type(4))) float f32x4;

static __device__ __forceinline__ unsigned short f2bf(float f) {
  union { float f; uint32_t u; } v; v.f = f;
  return (unsigned short)((v.u + 0x7fffu + ((v.u >> 16) & 1u)) >> 16);  // RNE
}
static __device__ __forceinline__ float bf2f(unsigned short h) {
  union { uint32_t u; float f; } v; v.u = ((uint32_t)h) << 16;
  return v.f;
}

// async global->LDS, 16B per lane; LDS dest must be wave-uniform (HW adds lane*16)
static __device__ __forceinline__ void gll16(const void* g, const void* l) {
  __builtin_amdgcn_global_load_lds(
      (const __attribute__((address_space(1))) unsigned int*)g,
      (__attribute__((address_space(3))) unsigned int*)l, 16, 0, 0);
}

// Stage a 128x64 bf16 tile (16KB) from global (row stride `ld` elems) into LDS.
// LDS dest is linear; SOURCE is pre-swizzled so that a swizzled READ
// (chunk ^ (row&7)) sees the logical layout (T2 / m201 stage_rc pattern).
static __device__ __forceinline__ void stage128x64(
    const unsigned short* g, int ld, unsigned short* lds, int tid) {
  const int lane = tid & 63, wave = tid >> 6;
#pragma unroll
  for (int inst = 0; inst < 4; ++inst) {
    const int off = inst * 4096 + wave * 1024;  // wave-uniform LDS byte offset
    const int byte = off + lane * 16;
    const int row = byte >> 7;                  // 128B per row (64 bf16)
    const int lc = ((byte >> 4) & 7) ^ (row & 7);  // logical 16B chunk
    gll16(g + (size_t)row * ld + lc * 8, (const char*)lds + off);
  }
}

// swizzled LDS fragment read: 8 bf16 (16B) at logical (row, 16B-chunk)
static __device__ __forceinline__ short8 frag(const unsigned short* lds, int r, int chunk) {
  return *(const short8*)((const char*)lds + r * 128 + ((chunk ^ (r & 7)) << 4));
}

// ---------------- weight transpose+convert: f32 [R][C] -> bf16 [C][R] ----------------
__global__ __launch_bounds__(256) void transpose_convert(
    const float* __restrict__ in, unsigned short* __restrict__ outp, int R, int C) {
  __shared__ float t[64][68];
  const size_t eo = (size_t)blockIdx.z * R * C;
  const float* src = in + eo + (size_t)(blockIdx.x * 64) * C + blockIdx.y * 64;
  unsigned short* dst = outp + eo + (size_t)(blockIdx.y * 64) * R + blockIdx.x * 64;
  const int tid = threadIdx.x;
  const int lr = tid >> 2, lc = (tid & 3) * 16;
#pragma unroll
  for (int q = 0; q < 4; ++q) {
    const f32x4 v = *(const f32x4*)(src + (size_t)lr * C + lc + 4 * q);
    t[lr][lc + 4 * q + 0] = v[0]; t[lr][lc + 4 * q + 1] = v[1];
    t[lr][lc + 4 * q + 2] = v[2]; t[lr][lc + 4 * q + 3] = v[3];
  }
  __syncthreads();
  unsigned short b[16];
#pragma unroll
  for (int q = 0; q < 16; ++q) b[q] = f2bf(t[lc + q][lr]);
  *(short8*)(dst + (size_t)lr * R + lc) = *(const short8*)&b[0];
  *(short8*)(dst + (size_t)lr * R + lc + 8) = *(const short8*)&b[8];
}

// ---------------- gate: logits (bf16-emulated), top-2, combine, probs, topk ----------------
__global__ __launch_bounds__(256) void gate_kernel(
    const float* __restrict__ x, const float* __restrict__ gw,
    float* __restrict__ combine, float* __restrict__ probs, int2* __restrict__ topk) {
  const int lane = threadIdx.x & 63;
  const int wave = threadIdx.x >> 6;
  const int t = blockIdx.x * 4 + wave;
  const float* xr = x + (size_t)t * DD;
  float acc[EE];
#pragma unroll
  for (int e = 0; e < EE; ++e) acc[e] = 0.f;
  for (int i = 0; i < DD / 64; ++i) {
    const int d = i * 64 + lane;
    const float xv = bf2f(f2bf(xr[d]));
#pragma unroll
    for (int e = 0; e < EE; ++e)
      acc[e] += xv * bf2f(f2bf(gw[e * DD + d]));
  }
#pragma unroll
  for (int e = 0; e < EE; ++e) {
#pragma unroll
    for (int off = 32; off > 0; off >>= 1)
      acc[e] += __shfl_xor(acc[e], off, 64);
  }
  if (lane == 0) {
    float lg[EE];
#pragma unroll
    for (int e = 0; e < EE; ++e) lg[e] = bf2f(f2bf(acc[e]));  // ref rounds matmul out to bf16
    float m1 = -1e30f, m2 = -1e30f; int i1 = 0, i2 = 0;
#pragma unroll
    for (int e = 0; e < EE; ++e) {
      const float v = lg[e];
      if (v > m1) { m2 = m1; i2 = i1; m1 = v; i1 = e; }
      else if (v > m2) { m2 = v; i2 = e; }
    }
    const float e2 = expf(m2 - m1);
    const float w1 = 1.f / (1.f + e2);
    const float w2 = e2 * w1;
    float cb[EE];
#pragma unroll
    for (int e = 0; e < EE; ++e) cb[e] = 0.f;
    cb[i1] = w1; cb[i2] += w2;
    float p[EE]; float s = 0.f;
#pragma unroll
    for (int e = 0; e < EE; ++e) { p[e] = expf(lg[e] - m1); s += p[e]; }
    const float inv = 1.f / s;
#pragma unroll
    for (int e = 0; e < EE; ++e) {
      combine[(size_t)t * EE + e] = cb[e];
      probs[(size_t)t * EE + e] = p[e] * inv;
    }
    topk[t] = make_int2(i1, i2);
  }
}

// ---------------- deterministic probs reduction -> mean_probs + loss ----------------
__global__ __launch_bounds__(256) void reduce_kernel(
    const float* __restrict__ probs, float* __restrict__ tail) {
  const int tid = threadIdx.x;
  const int lane = tid & 63, wave = tid >> 6;
  float acc[EE];
#pragma unroll
  for (int e = 0; e < EE; ++e) acc[e] = 0.f;
  for (int t = tid; t < TT; t += 256) {
#pragma unroll
    for (int e = 0; e < EE; ++e) acc[e] += probs[(size_t)t * EE + e];
  }
#pragma unroll
  for (int e = 0; e < EE; ++e) {
#pragma unroll
    for (int off = 32; off > 0; off >>= 1)
      acc[e] += __shfl_xor(acc[e], off, 64);
  }
  __shared__ float sm[4][EE];
  if (lane == 0) {
#pragma unroll
    for (int e = 0; e < EE; ++e) sm[wave][e] = acc[e];
  }
  __syncthreads();
  if (tid == 0) {
    float loss = 0.f;
#pragma unroll
    for (int e = 0; e < EE; ++e) {
      const float m = (sm[0][e] + sm[1][e] + sm[2][e] + sm[3][e]) * (1.f / TT);
      tail[1 + e] = m;
      loss += m * m;
    }
    tail[0] = (float)EE * loss;
  }
}

// ---------------- routing: per-expert compacted token lists + tile table ----------------
__global__ __launch_bounds__(512) void route_kernel(
    const int2* __restrict__ topk, const float* __restrict__ combine,
    int* __restrict__ tok_list, float* __restrict__ wt_list, int* __restrict__ tile_tab) {
  const int lane = threadIdx.x & 63;
  const int e = threadIdx.x >> 6;  // one wave per expert
  __shared__ int cnts[EE], offs[EE];
  int cnt = 0;
  for (int i = 0; i < TT / 64; ++i) {
    const int2 k2 = topk[i * 64 + lane];
    cnt += __popcll(__ballot(k2.x == e || k2.y == e));
  }
  if (lane == 0) cnts[e] = cnt;
  __syncthreads();
  if (threadIdx.x == 0) {
    int off = 0, nt = 0;
    for (int f = 0; f < EE; ++f) {
      offs[f] = off;
      const int pc = (cnts[f] + 127) & ~127;
      for (int j = 0; j < (pc >> 7); ++j) {
        tile_tab[2 * nt] = f; tile_tab[2 * nt + 1] = off + 128 * j; ++nt;
      }
      off += pc;
    }
    for (; nt < MAXT; ++nt) { tile_tab[2 * nt] = -1; tile_tab[2 * nt + 1] = 0; }
  }
  __syncthreads();
  int pos = offs[e];
  for (int i = 0; i < TT / 64; ++i) {
    const int t = i * 64 + lane;
    const int2 k2 = topk[t];
    const bool sel = (k2.x == e || k2.y == e);
    const unsigned long long m = __ballot(sel);
    if (sel) {
      const int p = pos + __popcll(m & ((1ull << lane) - 1ull));
      tok_list[p] = t;
      wt_list[p] = combine[(size_t)t * EE + e];
    }
    pos += __popcll(m);
  }
  const int pc = (cnt + 127) & ~127;  // pad slots: token 0, weight 0
  for (int s = cnt + lane; s < pc; s += 64) {
    tok_list[offs[e] + s] = 0;
    wt_list[offs[e] + s] = 0.f;
  }
}

// ---------------- gather x rows (f32 -> bf16) into contiguous padded buffer ----------------
__global__ __launch_bounds__(256) void gather_x(
    const float* __restrict__ x, const int* __restrict__ tok_list,
    const int* __restrict__ tile_tab, unsigned short* __restrict__ xg) {
  const int e = tile_tab[2 * blockIdx.x];
  if (e < 0) return;
  const int row0 = tile_tab[2 * blockIdx.x + 1] + blockIdx.y * 16;
  const int tid = threadIdx.x;
#pragma unroll
  for (int i = 0; i < 16; ++i) {
    const int row = row0 + i;
    const int tok = tok_list[row];
    const f32x4 v = *(const f32x4*)(x + (size_t)tok * DD + tid * 4);
    unsigned short b[4] = {f2bf(v[0]), f2bf(v[1]), f2bf(v[2]), f2bf(v[3])};
    *(short4v*)(xg + (size_t)row * DD + tid * 4) = *(const short4v*)b;
  }
}

// ---------------- grouped gate+up GEMM: act = bf16(silu(X@Wg) * (X@Wu)) ----------------
__global__ __launch_bounds__(256) void gemm_gu(
    const unsigned short* __restrict__ xg, const unsigned short* __restrict__ wgT,
    const unsigned short* __restrict__ wuT, const int* __restrict__ tile_tab,
    unsigned short* __restrict__ act) {
  __shared__ unsigned short As[128 * 64], Bgs[128 * 64], Bus[128 * 64];
  const int e = tile_tab[2 * blockIdx.x];
  if (e < 0) return;
  const int row0 = tile_tab[2 * blockIdx.x + 1];
  const int n0 = blockIdx.y * 128;
  const int tid = threadIdx.x, lane = tid & 63, wave = tid >> 6;
  const int wm = (wave >> 1) * 64, wn = (wave & 1) * 64;
  const int fr = lane & 15, hi = lane >> 4;

  const unsigned short* A = xg + (size_t)row0 * DD;
  const unsigned short* G = wgT + ((size_t)e * HH + n0) * DD;
  const unsigned short* U = wuT + ((size_t)e * HH + n0) * DD;

  f32x4 accG[4][4], accU[4][4];
#pragma unroll
  for (int i = 0; i < 4; ++i)
#pragma unroll
    for (int j = 0; j < 4; ++j) {
      accG[i][j] = (f32x4){0.f, 0.f, 0.f, 0.f};
      accU[i][j] = (f32x4){0.f, 0.f, 0.f, 0.f};
    }

  for (int k0 = 0; k0 < DD; k0 += 64) {
    stage128x64(A + k0, DD, As, tid);
    stage128x64(G + k0, DD, Bgs, tid);
    stage128x64(U + k0, DD, Bus, tid);
    __syncthreads();  // compiler drains vmcnt before s_barrier
#pragma unroll
    for (int kk = 0; kk < 2; ++kk) {
      const int ch = kk * 4 + hi;
      short8 a[4], bg[4], bu[4];
#pragma unroll
      for (int i = 0; i < 4; ++i) a[i] = frag(As, wm + i * 16 + fr, ch);
#pragma unroll
      for (int j = 0; j < 4; ++j) {
        bg[j] = frag(Bgs, wn + j * 16 + fr, ch);
        bu[j] = frag(Bus, wn + j * 16 + fr, ch);
      }
#pragma unroll
      for (int i = 0; i < 4; ++i)
#pragma unroll
        for (int j = 0; j < 4; ++j) {
          accG[i][j] = __builtin_amdgcn_mfma_f32_16x16x32_bf16(a[i], bg[j], accG[i][j], 0, 0, 0);
          accU[i][j] = __builtin_amdgcn_mfma_f32_16x16x32_bf16(a[i], bu[j], accU[i][j], 0, 0, 0);
        }
    }
    __syncthreads();
  }
  const int r4 = hi * 4;
#pragma unroll
  for (int i = 0; i < 4; ++i)
#pragma unroll
    for (int j = 0; j < 4; ++j)
#pragma unroll
      for (int r = 0; r < 4; ++r) {
        const int row = row0 + wm + i * 16 + r4 + r;
        const int col = n0 + wn + j * 16 + fr;
        const float gg = accG[i][j][r], uu = accU[i][j][r];
        act[(size_t)row * HH + col] = f2bf((gg / (1.f + expf(-gg))) * uu);
      }
}

// ---------------- grouped down GEMM + atomic scatter (exactly 2 adds/elem) ----------------
__global__ __launch_bounds__(256) void gemm_down(
    const unsigned short* __restrict__ act, const unsigned short* __restrict__ wdT,
    const int* __restrict__ tile_tab, const int* __restrict__ tok_list,
    const float* __restrict__ wt_list, float* __restrict__ out) {
  __shared__ unsigned short As[128 * 64], Bs[128 * 64];
  const int e = tile_tab[2 * blockIdx.x];
  if (e < 0) return;
  const int row0 = tile_tab[2 * blockIdx.x + 1];
  const int n0 = blockIdx.y * 128;
  const int tid = threadIdx.x, lane = tid & 63, wave = tid >> 6;
  const int wm = (wave >> 1) * 64, wn = (wave & 1) * 64;
  const int fr = lane & 15, hi = lane >> 4;

  const unsigned short* A = act + (size_t)row0 * HH;
  const unsigned short* Bm = wdT + ((size_t)e * DD + n0) * HH;

  f32x4 acc[4][4];
#pragma unroll
  for (int i = 0; i < 4; ++i)
#pragma unroll
    for (int j = 0; j < 4; ++j) acc[i][j] = (f32x4){0.f, 0.f, 0.f, 0.f};

  for (int k0 = 0; k0 < HH; k0 += 64) {
    stage128x64(A + k0, HH, As, tid);
    stage128x64(Bm + k0, HH, Bs, tid);
    __syncthreads();
#pragma unroll
    for (int kk = 0; kk < 2; ++kk) {
      const int ch = kk * 4 + hi;
      short8 a[4], b[4];
#pragma unroll
      for (int i = 0; i < 4; ++i) a[i] = frag(As, wm + i * 16 + fr, ch);
#pragma unroll
      for (int j = 0; j < 4; ++j) b[j] = frag(Bs, wn + j * 16 + fr, ch);
#pragma unroll
      for (int i = 0; i < 4; ++i)
#pragma unroll
        for (int j = 0; j < 4; ++j)
          acc[i][j] = __builtin_amdgcn_mfma_f32_16x16x32_bf16(a[i], b[j], acc[i][j], 0, 0, 0);
    }
    __syncthreads();
  }
  const int r4 = hi * 4;
#pragma unroll
  for (int i = 0; i < 4; ++i)
#pragma unroll
    for (int r = 0; r < 4; ++r) {
      const int rl = row0 + wm + i * 16 + r4 + r;
      const int tok = tok_list[rl];
      const float wt = wt_list[rl];
      if (wt != 0.f) {
#pragma unroll
        for (int j = 0; j < 4; ++j) {
          const int col = n0 + wn + j * 16 + fr;
          unsafeAtomicAdd(&out[(size_t)tok * DD + col], acc[i][j][r] * wt);
        }
      }
    }
}

extern "C" void kernel_launch(void* const* d_in, const int* in_sizes, int n_in,
                              void* d_out, int out_size, void* d_ws, size_t ws_size,
                              hipStream_t stream) {
  const float* x      = (const float*)d_in[0];
  const float* gw     = (const float*)d_in[1];
  const float* w_gate = (const float*)d_in[2];
  const float* w_up   = (const float*)d_in[3];
  const float* w_down = (const float*)d_in[4];
  float* out = (float*)d_out;
  float* tail = out + (size_t)TT * DD;  // [loss, mean_probs x 8]

  char* w = (char*)d_ws;
  size_t o = 0;
  auto carve = [&](size_t bytes) { char* p = w + o; o += (bytes + 255) & ~255ull; return p; };
  unsigned short* wgT = (unsigned short*)carve((size_t)EE * HH * DD * 2);  // [E][H][D] bf16
  unsigned short* wuT = (unsigned short*)carve((size_t)EE * HH * DD * 2);  // [E][H][D] bf16
  unsigned short* wdT = (unsigned short*)carve((size_t)EE * DD * HH * 2);  // [E][D][H] bf16
  unsigned short* xg  = (unsigned short*)carve((size_t)MP * DD * 2);       // gathered x bf16
  unsigned short* act = (unsigned short*)carve((size_t)MP * HH * 2);       // gathered act bf16
  float* combine = (float*)carve((size_t)TT * EE * 4);
  float* probs   = (float*)carve((size_t)TT * EE * 4);
  int2* topk     = (int2*)carve((size_t)TT * 8);
  int* tok_list  = (int*)carve((size_t)MP * 4);
  float* wt_list = (float*)carve((size_t)MP * 4);
  int* tile_tab  = (int*)carve((size_t)MAXT * 8);

  hipMemsetAsync(out, 0, (size_t)TT * DD * sizeof(float), stream);

  transpose_convert<<<dim3(DD / 64, HH / 64, EE), 256, 0, stream>>>(w_gate, wgT, DD, HH);
  transpose_convert<<<dim3(DD / 64, HH / 64, EE), 256, 0, stream>>>(w_up, wuT, DD, HH);
  transpose_convert<<<dim3(HH / 64, DD / 64, EE), 256, 0, stream>>>(w_down, wdT, HH, DD);

  gate_kernel<<<TT / 4, 256, 0, stream>>>(x, gw, combine, probs, topk);
  reduce_kernel<<<1, 256, 0, stream>>>(probs, tail);
  route_kernel<<<1, 512, 0, stream>>>(topk, combine, tok_list, wt_list, tile_tab);
  gather_x<<<dim3(MAXT, 8), 256, 0, stream>>>(x, tok_list, tile_tab, xg);

  gemm_gu<<<dim3(MAXT, HH / 128), 256, 0, stream>>>(xg, wgT, wuT, tile_tab, act);
  gemm_down<<<dim3(MAXT, DD / 128), 256, 0, stream>>>(act, wdT, tile_tab, tok_list, wt_list, out);
}

// Round 3
// 328.696 us; speedup vs baseline: 9.6731x; 1.1404x over previous
//
#include <hip/hip_runtime.h>
#include <stdint.h>

#define TT 4096    // B*S tokens
#define DD 1024    // model dim
#define EE 8       // experts
#define HH 1792    // hidden dim
#define MP 10240   // max padded gathered rows (40*256)
#define MT256 40   // max 256-row tiles
#define MT128 80   // max 128-row tiles

typedef __attribute__((ext_vector_type(8))) short short8;    // 8 x bf16
typedef __attribute__((ext_vector_type(4))) short short4v;   // 4 x bf16
typedef __attribute__((ext_vector_type(4))) float f32x4;

static __device__ __forceinline__ unsigned short f2bf(float f) {
  union { float f; uint32_t u; } v; v.f = f;
  return (unsigned short)((v.u + 0x7fffu + ((v.u >> 16) & 1u)) >> 16);  // RNE
}
static __device__ __forceinline__ float bf2f(unsigned short h) {
  union { uint32_t u; float f; } v; v.u = ((uint32_t)h) << 16;
  return v.f;
}

// async global->LDS, 16B/lane; LDS dest wave-uniform (HW adds lane*16)
static __device__ __forceinline__ void gll16(const void* g, const void* l) {
  __builtin_amdgcn_global_load_lds(
      (const __attribute__((address_space(1))) unsigned int*)g,
      (__attribute__((address_space(3))) unsigned int*)l, 16, 0, 0);
}

// ---------------- weight transpose+convert: f32 [R][C] -> bf16 [C][R] ----------------
// ilv=1: dst row for source col c is (c>>4)*32 + sel*16 + (c&15)  (G/U 16-col interleave)
__global__ __launch_bounds__(256) void transpose_convert(
    const float* __restrict__ in, unsigned short* __restrict__ outp, int R, int C,
    int ilv, int sel) {
  __shared__ float t[64][68];
  const float* src = in + (size_t)blockIdx.z * R * C + (size_t)(blockIdx.x * 64) * C +
                     blockIdx.y * 64;
  unsigned short* dst = outp + (size_t)blockIdx.z * R * C * (ilv ? 2 : 1);
  const int tid = threadIdx.x;
  const int lr = tid >> 2, lc = (tid & 3) * 16;
#pragma unroll
  for (int q = 0; q < 4; ++q) {
    const f32x4 v = *(const f32x4*)(src + (size_t)lr * C + lc + 4 * q);
    t[lr][lc + 4 * q + 0] = v[0]; t[lr][lc + 4 * q + 1] = v[1];
    t[lr][lc + 4 * q + 2] = v[2]; t[lr][lc + 4 * q + 3] = v[3];
  }
  __syncthreads();
  unsigned short b[16];
#pragma unroll
  for (int q = 0; q < 16; ++q) b[q] = f2bf(t[lc + q][lr]);
  const int cg = blockIdx.y * 64 + lr;                       // source col (dst logical row)
  const int prow = ilv ? ((cg >> 4) * 32 + sel * 16 + (cg & 15)) : cg;
  unsigned short* d = dst + (size_t)prow * R + blockIdx.x * 64 + lc;
  *(short8*)(d) = *(const short8*)&b[0];
  *(short8*)(d + 8) = *(const short8*)&b[8];
}

// ---------------- gate: logits (bf16-emulated), top-2, combine, probs, topk ----------------
__global__ __launch_bounds__(256) void gate_kernel(
    const float* __restrict__ x, const float* __restrict__ gw,
    float* __restrict__ combine, float* __restrict__ probs, int2* __restrict__ topk) {
  const int lane = threadIdx.x & 63;
  const int wave = threadIdx.x >> 6;
  const int t = blockIdx.x * 4 + wave;
  const float* xr = x + (size_t)t * DD;
  float acc[EE];
#pragma unroll
  for (int e = 0; e < EE; ++e) acc[e] = 0.f;
  for (int i = 0; i < DD / 64; ++i) {
    const int d = i * 64 + lane;
    const float xv = bf2f(f2bf(xr[d]));
#pragma unroll
    for (int e = 0; e < EE; ++e)
      acc[e] += xv * bf2f(f2bf(gw[e * DD + d]));
  }
#pragma unroll
  for (int e = 0; e < EE; ++e) {
#pragma unroll
    for (int off = 32; off > 0; off >>= 1)
      acc[e] += __shfl_xor(acc[e], off, 64);
  }
  if (lane == 0) {
    float lg[EE];
#pragma unroll
    for (int e = 0; e < EE; ++e) lg[e] = bf2f(f2bf(acc[e]));
    float m1 = -1e30f, m2 = -1e30f; int i1 = 0, i2 = 0;
#pragma unroll
    for (int e = 0; e < EE; ++e) {
      const float v = lg[e];
      if (v > m1) { m2 = m1; i2 = i1; m1 = v; i1 = e; }
      else if (v > m2) { m2 = v; i2 = e; }
    }
    const float e2 = expf(m2 - m1);
    const float w1 = 1.f / (1.f + e2);
    const float w2 = e2 * w1;
    float cb[EE];
#pragma unroll
    for (int e = 0; e < EE; ++e) cb[e] = 0.f;
    cb[i1] = w1; cb[i2] += w2;
    float p[EE]; float s = 0.f;
#pragma unroll
    for (int e = 0; e < EE; ++e) { p[e] = expf(lg[e] - m1); s += p[e]; }
    const float inv = 1.f / s;
#pragma unroll
    for (int e = 0; e < EE; ++e) {
      combine[(size_t)t * EE + e] = cb[e];
      probs[(size_t)t * EE + e] = p[e] * inv;
    }
    topk[t] = make_int2(i1, i2);
  }
}

// ---------------- deterministic probs reduction -> mean_probs + loss ----------------
__global__ __launch_bounds__(256) void reduce_kernel(
    const float* __restrict__ probs, float* __restrict__ tail) {
  const int tid = threadIdx.x;
  const int lane = tid & 63, wave = tid >> 6;
  float acc[EE];
#pragma unroll
  for (int e = 0; e < EE; ++e) acc[e] = 0.f;
  for (int t = tid; t < TT; t += 256) {
#pragma unroll
    for (int e = 0; e < EE; ++e) acc[e] += probs[(size_t)t * EE + e];
  }
#pragma unroll
  for (int e = 0; e < EE; ++e) {
#pragma unroll
    for (int off = 32; off > 0; off >>= 1)
      acc[e] += __shfl_xor(acc[e], off, 64);
  }
  __shared__ float sm[4][EE];
  if (lane == 0) {
#pragma unroll
    for (int e = 0; e < EE; ++e) sm[wave][e] = acc[e];
  }
  __syncthreads();
  if (tid == 0) {
    float loss = 0.f;
#pragma unroll
    for (int e = 0; e < EE; ++e) {
      const float m = (sm[0][e] + sm[1][e] + sm[2][e] + sm[3][e]) * (1.f / TT);
      tail[1 + e] = m;
      loss += m * m;
    }
    tail[0] = (float)EE * loss;
  }
}

// ---------------- routing: compacted token lists (pad to 256) + two tile tables ----------------
__global__ __launch_bounds__(512) void route_kernel(
    const int2* __restrict__ topk, const float* __restrict__ combine,
    int* __restrict__ tok_list, float* __restrict__ wt_list,
    int* __restrict__ tab256, int* __restrict__ tab128) {
  const int lane = threadIdx.x & 63;
  const int e = threadIdx.x >> 6;  // one wave per expert
  __shared__ int cnts[EE], offs[EE];
  int cnt = 0;
  for (int i = 0; i < TT / 64; ++i) {
    const int2 k2 = topk[i * 64 + lane];
    cnt += __popcll(__ballot(k2.x == e || k2.y == e));
  }
  if (lane == 0) cnts[e] = cnt;
  __syncthreads();
  if (threadIdx.x == 0) {
    int off = 0, n256 = 0, n128 = 0;
    for (int f = 0; f < EE; ++f) {
      offs[f] = off;
      const int pc = (cnts[f] + 255) & ~255;
      for (int j = 0; j < (pc >> 8); ++j) {
        tab256[2 * n256] = f; tab256[2 * n256 + 1] = off + 256 * j; ++n256;
      }
      for (int j = 0; j < (pc >> 7); ++j) {
        tab128[2 * n128] = f; tab128[2 * n128 + 1] = off + 128 * j; ++n128;
      }
      off += pc;
    }
    for (; n256 < MT256; ++n256) { tab256[2 * n256] = -1; tab256[2 * n256 + 1] = 0; }
    for (; n128 < MT128; ++n128) { tab128[2 * n128] = -1; tab128[2 * n128 + 1] = 0; }
  }
  __syncthreads();
  int pos = offs[e];
  for (int i = 0; i < TT / 64; ++i) {
    const int t = i * 64 + lane;
    const int2 k2 = topk[t];
    const bool sel = (k2.x == e || k2.y == e);
    const unsigned long long m = __ballot(sel);
    if (sel) {
      const int p = pos + __popcll(m & ((1ull << lane) - 1ull));
      tok_list[p] = t;
      wt_list[p] = combine[(size_t)t * EE + e];
    }
    pos += __popcll(m);
  }
  const int pc = (cnt + 255) & ~255;  // pad slots: token 0, weight 0
  for (int s = cnt + lane; s < pc; s += 64) {
    tok_list[offs[e] + s] = 0;
    wt_list[offs[e] + s] = 0.f;
  }
}

// ---------------- gather x rows (f32 -> bf16) into contiguous padded buffer ----------------
__global__ __launch_bounds__(256) void gather_x(
    const float* __restrict__ x, const int* __restrict__ tok_list,
    const int* __restrict__ tab256, unsigned short* __restrict__ xg) {
  const int e = tab256[2 * blockIdx.x];
  if (e < 0) return;
  const int row0 = tab256[2 * blockIdx.x + 1] + blockIdx.y * 16;
  const int tid = threadIdx.x;
#pragma unroll
  for (int i = 0; i < 16; ++i) {
    const int row = row0 + i;
    const int tok = tok_list[row];
    const f32x4 v = *(const f32x4*)(x + (size_t)tok * DD + tid * 4);
    unsigned short b[4] = {f2bf(v[0]), f2bf(v[1]), f2bf(v[2]), f2bf(v[3])};
    *(short4v*)(xg + (size_t)row * DD + tid * 4) = *(const short4v*)b;
  }
}

// ---------------- grouped GEMM, ring-4 counted-vmcnt pipeline ----------------
// MODE 0: A=xg [row][DD], B=wguT [e][2H][DD] interleaved; epilogue silu(g)*u -> act bf16
// MODE 1: A=act [row][HH], B=wdT [e][DD][HH]; epilogue atomic scatter * combine wt
template <int MODE>
__global__ __launch_bounds__(512, 1) void gemm_main(
    const unsigned short* __restrict__ Ab, const unsigned short* __restrict__ Bb,
    const int* __restrict__ tab, const int* __restrict__ tok_list,
    const float* __restrict__ wt_list, unsigned short* __restrict__ act,
    float* __restrict__ out) {
  constexpr int K   = (MODE == 0) ? DD : HH;
  constexpr int BM  = (MODE == 0) ? 256 : 128;
  constexpr int BN  = 256;
  constexpr int NBR = (MODE == 0) ? 2 * HH : DD;   // B rows per expert
  constexpr int NK  = K / 32;                      // 32 / 56 K-steps
  constexpr int SLOTB = (BM + BN) * 64;            // LDS bytes per ring slot
  constexpr int GLL = SLOTB / 8192;                // gll insts per stage per thread (4 / 3)
  constexpr int NI  = ((MODE == 0) ? 128 : 64) / 16;
  constexpr int NNT = ((MODE == 0) ? 2 * HH : DD) / BN;  // 14 / 4
  extern __shared__ char lds[];

  // flattened grid, nt-fastest; XCD-chunk swizzle (grid % 8 == 0 for both modes)
  const int nwg = gridDim.x;
  const int wgid = (blockIdx.x & 7) * (nwg >> 3) + (blockIdx.x >> 3);
  const int mt = wgid / NNT, nt = wgid % NNT;
  const int e = tab[2 * mt];
  if (e < 0) return;
  const int row0 = tab[2 * mt + 1];
  const int n0 = nt * BN;

  const int tid = threadIdx.x, lane = tid & 63, wave = tid >> 6;
  const int wm = (wave >> 2) * ((MODE == 0) ? 128 : 64);
  const int wn = (wave & 3) * 64;
  const int fr = lane & 15, hi = lane >> 4;

  const unsigned short* At = Ab + (size_t)row0 * K;
  const unsigned short* Bt = Bb + ((size_t)e * NBR + n0) * K;

  // drain any vmem from the tab loads so vmcnt accounting below is exact
  asm volatile("s_waitcnt vmcnt(0)" ::: "memory");

  // stage K-tile t into ring slot: linear LDS, source pre-swizzled so that the
  // read-side chunk XOR (c ^ (r&3) ^ ((r>>2)&3)) sees the logical layout
  auto stage = [&](int t, int slot) {
    const unsigned short* As = At + t * 32;
    const unsigned short* Bs = Bt + t * 32;
#pragma unroll
    for (int q = 0; q < GLL; ++q) {
      const int rel = q * 8192 + wave * 1024 + lane * 16;  // byte within slot
      const bool isA = rel < BM * 64;                      // uniform per (q,wave)
      const int rb = isA ? rel : rel - BM * 64;
      const int row = rb >> 6;
      const int clog = ((rb >> 4) & 3) ^ (row & 3) ^ ((row >> 2) & 3);
      gll16((isA ? As : Bs) + (size_t)row * K + clog * 8,
            lds + slot * SLOTB + q * 8192 + wave * 1024);
    }
  };
  auto rdA = [&](int slot, int m) -> short8 {
    const int c = hi ^ (m & 3) ^ ((m >> 2) & 3);
    return *(const short8*)(lds + slot * SLOTB + m * 64 + (c << 4));
  };
  auto rdB = [&](int slot, int n) -> short8 {
    const int c = hi ^ (n & 3) ^ ((n >> 2) & 3);
    return *(const short8*)(lds + slot * SLOTB + BM * 64 + n * 64 + (c << 4));
  };

  f32x4 acc[NI][4];
#pragma unroll
  for (int i = 0; i < NI; ++i)
#pragma unroll
    for (int j = 0; j < 4; ++j) acc[i][j] = (f32x4){0.f, 0.f, 0.f, 0.f};

  stage(0, 0); stage(1, 1); stage(2, 2);  // prefetch depth 3

#pragma unroll 1
  for (int t = 0; t < NK; ++t) {
    // my tile-(t-1) LDS reads retired + my tile-t stage landed, THEN barrier:
    // after the barrier this holds for ALL waves -> reads of slot t&3 are safe
    // and overwriting slot (t-1)&3 is safe.
    asm volatile("s_waitcnt lgkmcnt(0)" ::: "memory");
    if constexpr (GLL == 4) asm volatile("s_waitcnt vmcnt(8)" ::: "memory");
    else                    asm volatile("s_waitcnt vmcnt(6)" ::: "memory");
    __builtin_amdgcn_sched_barrier(0);
    __builtin_amdgcn_s_barrier();
    __builtin_amdgcn_sched_barrier(0);
    int tp = t + 3; if (tp >= NK) tp -= NK;   // dummy re-stage at tail keeps counts uniform
    stage(tp, (t + 3) & 3);
    const int slot = t & 3;
    short8 a[NI], b[4];
#pragma unroll
    for (int i = 0; i < NI; ++i) a[i] = rdA(slot, wm + i * 16 + fr);
#pragma unroll
    for (int j = 0; j < 4; ++j) b[j] = rdB(slot, wn + j * 16 + fr);
    __builtin_amdgcn_s_setprio(1);
#pragma unroll
    for (int i = 0; i < NI; ++i)
#pragma unroll
      for (int j = 0; j < 4; ++j)
        acc[i][j] = __builtin_amdgcn_mfma_f32_16x16x32_bf16(a[i], b[j], acc[i][j], 0, 0, 0);
    __builtin_amdgcn_s_setprio(0);
  }
  asm volatile("s_waitcnt vmcnt(0)" ::: "memory");

  const int r4 = hi * 4;
  if constexpr (MODE == 0) {
#pragma unroll
    for (int i = 0; i < NI; ++i)
#pragma unroll
      for (int r = 0; r < 4; ++r) {
        const int row = row0 + wm + i * 16 + r4 + r;
#pragma unroll
        for (int jj = 0; jj < 2; ++jj) {
          const float g = acc[i][2 * jj][r], u = acc[i][2 * jj + 1][r];
          const int nb = n0 + wn + jj * 32;
          const int h = ((nb >> 5) << 4) + fr;   // de-interleave to real H col
          act[(size_t)row * HH + h] = f2bf((g / (1.f + expf(-g))) * u);
        }
      }
  } else {
#pragma unroll
    for (int i = 0; i < NI; ++i)
#pragma unroll
      for (int r = 0; r < 4; ++r) {
        const int rl = row0 + wm + i * 16 + r4 + r;
        const int tok = tok_list[rl];
        const float wt = wt_list[rl];
        if (wt != 0.f) {
#pragma unroll
          for (int j = 0; j < 4; ++j)
            unsafeAtomicAdd(&out[(size_t)tok * DD + n0 + wn + j * 16 + fr],
                            acc[i][j][r] * wt);
        }
      }
  }
}

extern "C" void kernel_launch(void* const* d_in, const int* in_sizes, int n_in,
                              void* d_out, int out_size, void* d_ws, size_t ws_size,
                              hipStream_t stream) {
  const float* x      = (const float*)d_in[0];
  const float* gw     = (const float*)d_in[1];
  const float* w_gate = (const float*)d_in[2];
  const float* w_up   = (const float*)d_in[3];
  const float* w_down = (const float*)d_in[4];
  float* out = (float*)d_out;
  float* tail = out + (size_t)TT * DD;  // [loss, mean_probs x 8]

  char* w = (char*)d_ws;
  size_t o = 0;
  auto carve = [&](size_t bytes) { char* p = w + o; o += (bytes + 255) & ~255ull; return p; };
  unsigned short* wguT = (unsigned short*)carve((size_t)EE * 2 * HH * DD * 2);  // interleaved G/U
  unsigned short* wdT  = (unsigned short*)carve((size_t)EE * DD * HH * 2);
  unsigned short* xg   = (unsigned short*)carve((size_t)MP * DD * 2);
  unsigned short* act  = (unsigned short*)carve((size_t)MP * HH * 2);
  float* combine = (float*)carve((size_t)TT * EE * 4);
  float* probs   = (float*)carve((size_t)TT * EE * 4);
  int2* topk     = (int2*)carve((size_t)TT * 8);
  int* tok_list  = (int*)carve((size_t)MP * 4);
  float* wt_list = (float*)carve((size_t)MP * 4);
  int* tab256    = (int*)carve((size_t)MT256 * 8);
  int* tab128    = (int*)carve((size_t)MT128 * 8);

  hipMemsetAsync(out, 0, (size_t)TT * DD * sizeof(float), stream);

  transpose_convert<<<dim3(DD / 64, HH / 64, EE), 256, 0, stream>>>(w_gate, wguT, DD, HH, 1, 0);
  transpose_convert<<<dim3(DD / 64, HH / 64, EE), 256, 0, stream>>>(w_up,   wguT, DD, HH, 1, 1);
  transpose_convert<<<dim3(HH / 64, DD / 64, EE), 256, 0, stream>>>(w_down, wdT,  HH, DD, 0, 0);

  gate_kernel<<<TT / 4, 256, 0, stream>>>(x, gw, combine, probs, topk);
  reduce_kernel<<<1, 256, 0, stream>>>(probs, tail);
  route_kernel<<<1, 512, 0, stream>>>(topk, combine, tok_list, wt_list, tab256, tab128);
  gather_x<<<dim3(MT256, 16), 256, 0, stream>>>(x, tok_list, tab256, xg);

  hipFuncSetAttribute(reinterpret_cast<const void*>(&gemm_main<0>),
                      hipFuncAttributeMaxDynamicSharedMemorySize, 131072);
  hipFuncSetAttribute(reinterpret_cast<const void*>(&gemm_main<1>),
                      hipFuncAttributeMaxDynamicSharedMemorySize, 98304);

  gemm_main<0><<<MT256 * 14, 512, 131072, stream>>>(xg, wguT, tab256, nullptr, nullptr, act, nullptr);
  gemm_main<1><<<MT128 * 4, 512, 98304, stream>>>(act, wdT, tab128, tok_list, wt_list, nullptr, out);
}

// Round 4
// 298.166 us; speedup vs baseline: 10.6636x; 1.1024x over previous
//
#include <hip/hip_runtime.h>
#include <stdint.h>

#define TT 4096    // B*S tokens
#define DD 1024    // model dim
#define EE 8       // experts
#define HH 1792    // hidden dim
#define MP 10240   // max padded gathered rows (40*256)
#define MT256 40   // max 256-row tiles
#define MT128 80   // max 128-row tiles

typedef __attribute__((ext_vector_type(8))) short short8;    // 8 x bf16
typedef __attribute__((ext_vector_type(4))) short short4v;   // 4 x bf16
typedef __attribute__((ext_vector_type(4))) float f32x4;

static __device__ __forceinline__ unsigned short f2bf(float f) {
  union { float f; uint32_t u; } v; v.f = f;
  return (unsigned short)((v.u + 0x7fffu + ((v.u >> 16) & 1u)) >> 16);  // RNE
}
static __device__ __forceinline__ float bf2f(unsigned short h) {
  union { uint32_t u; float f; } v; v.u = ((uint32_t)h) << 16;
  return v.f;
}

// async global->LDS, 16B/lane; LDS dest wave-uniform (HW adds lane*16)
static __device__ __forceinline__ void gll16(const void* g, const void* l) {
  __builtin_amdgcn_global_load_lds(
      (const __attribute__((address_space(1))) unsigned int*)g,
      (__attribute__((address_space(3))) unsigned int*)l, 16, 0, 0);
}

// ---------------- weight transpose+convert: f32 [R][C] -> bf16 [C][R] ----------------
// ilv=1: dst row for source col c is (c>>4)*32 + sel*16 + (c&15)  (G/U 16-col interleave)
__global__ __launch_bounds__(256) void transpose_convert(
    const float* __restrict__ in, unsigned short* __restrict__ outp, int R, int C,
    int ilv, int sel) {
  __shared__ float t[64][68];
  const float* src = in + (size_t)blockIdx.z * R * C + (size_t)(blockIdx.x * 64) * C +
                     blockIdx.y * 64;
  unsigned short* dst = outp + (size_t)blockIdx.z * R * C * (ilv ? 2 : 1);
  const int tid = threadIdx.x;
  const int lr = tid >> 2, lc = (tid & 3) * 16;
#pragma unroll
  for (int q = 0; q < 4; ++q) {
    const f32x4 v = *(const f32x4*)(src + (size_t)lr * C + lc + 4 * q);
    t[lr][lc + 4 * q + 0] = v[0]; t[lr][lc + 4 * q + 1] = v[1];
    t[lr][lc + 4 * q + 2] = v[2]; t[lr][lc + 4 * q + 3] = v[3];
  }
  __syncthreads();
  unsigned short b[16];
#pragma unroll
  for (int q = 0; q < 16; ++q) b[q] = f2bf(t[lc + q][lr]);
  const int cg = blockIdx.y * 64 + lr;                       // source col (dst logical row)
  const int prow = ilv ? ((cg >> 4) * 32 + sel * 16 + (cg & 15)) : cg;
  unsigned short* d = dst + (size_t)prow * R + blockIdx.x * 64 + lc;
  *(short8*)(d) = *(const short8*)&b[0];
  *(short8*)(d + 8) = *(const short8*)&b[8];
}

// ---------------- gate: logits (bf16-emulated), top-2, combine, probs, topk ----------------
__global__ __launch_bounds__(256) void gate_kernel(
    const float* __restrict__ x, const float* __restrict__ gw,
    float* __restrict__ combine, float* __restrict__ probs, int2* __restrict__ topk) {
  const int lane = threadIdx.x & 63;
  const int wave = threadIdx.x >> 6;
  const int t = blockIdx.x * 4 + wave;
  const float* xr = x + (size_t)t * DD;
  float acc[EE];
#pragma unroll
  for (int e = 0; e < EE; ++e) acc[e] = 0.f;
  for (int i = 0; i < DD / 64; ++i) {
    const int d = i * 64 + lane;
    const float xv = bf2f(f2bf(xr[d]));
#pragma unroll
    for (int e = 0; e < EE; ++e)
      acc[e] += xv * bf2f(f2bf(gw[e * DD + d]));
  }
#pragma unroll
  for (int e = 0; e < EE; ++e) {
#pragma unroll
    for (int off = 32; off > 0; off >>= 1)
      acc[e] += __shfl_xor(acc[e], off, 64);
  }
  if (lane == 0) {
    float lg[EE];
#pragma unroll
    for (int e = 0; e < EE; ++e) lg[e] = bf2f(f2bf(acc[e]));
    float m1 = -1e30f, m2 = -1e30f; int i1 = 0, i2 = 0;
#pragma unroll
    for (int e = 0; e < EE; ++e) {
      const float v = lg[e];
      if (v > m1) { m2 = m1; i2 = i1; m1 = v; i1 = e; }
      else if (v > m2) { m2 = v; i2 = e; }
    }
    const float e2 = expf(m2 - m1);
    const float w1 = 1.f / (1.f + e2);
    const float w2 = e2 * w1;
    float cb[EE];
#pragma unroll
    for (int e = 0; e < EE; ++e) cb[e] = 0.f;
    cb[i1] = w1; cb[i2] += w2;
    float p[EE]; float s = 0.f;
#pragma unroll
    for (int e = 0; e < EE; ++e) { p[e] = expf(lg[e] - m1); s += p[e]; }
    const float inv = 1.f / s;
#pragma unroll
    for (int e = 0; e < EE; ++e) {
      combine[(size_t)t * EE + e] = cb[e];
      probs[(size_t)t * EE + e] = p[e] * inv;
    }
    topk[t] = make_int2(i1, i2);
  }
}

// ---------------- deterministic probs reduction -> mean_probs + loss ----------------
__global__ __launch_bounds__(256) void reduce_kernel(
    const float* __restrict__ probs, float* __restrict__ tail) {
  const int tid = threadIdx.x;
  const int lane = tid & 63, wave = tid >> 6;
  float acc[EE];
#pragma unroll
  for (int e = 0; e < EE; ++e) acc[e] = 0.f;
  for (int t = tid; t < TT; t += 256) {
#pragma unroll
    for (int e = 0; e < EE; ++e) acc[e] += probs[(size_t)t * EE + e];
  }
#pragma unroll
  for (int e = 0; e < EE; ++e) {
#pragma unroll
    for (int off = 32; off > 0; off >>= 1)
      acc[e] += __shfl_xor(acc[e], off, 64);
  }
  __shared__ float sm[4][EE];
  if (lane == 0) {
#pragma unroll
    for (int e = 0; e < EE; ++e) sm[wave][e] = acc[e];
  }
  __syncthreads();
  if (tid == 0) {
    float loss = 0.f;
#pragma unroll
    for (int e = 0; e < EE; ++e) {
      const float m = (sm[0][e] + sm[1][e] + sm[2][e] + sm[3][e]) * (1.f / TT);
      tail[1 + e] = m;
      loss += m * m;
    }
    tail[0] = (float)EE * loss;
  }
}

// ---------------- routing: compacted token lists (pad to 256) + two tile tables ----------------
__global__ __launch_bounds__(512) void route_kernel(
    const int2* __restrict__ topk, const float* __restrict__ combine,
    int* __restrict__ tok_list, float* __restrict__ wt_list,
    int* __restrict__ tab256, int* __restrict__ tab128) {
  const int lane = threadIdx.x & 63;
  const int e = threadIdx.x >> 6;  // one wave per expert
  __shared__ int cnts[EE], offs[EE];
  int cnt = 0;
  for (int i = 0; i < TT / 64; ++i) {
    const int2 k2 = topk[i * 64 + lane];
    cnt += __popcll(__ballot(k2.x == e || k2.y == e));
  }
  if (lane == 0) cnts[e] = cnt;
  __syncthreads();
  if (threadIdx.x == 0) {
    int off = 0, n256 = 0, n128 = 0;
    for (int f = 0; f < EE; ++f) {
      offs[f] = off;
      const int pc = (cnts[f] + 255) & ~255;
      for (int j = 0; j < (pc >> 8); ++j) {
        tab256[2 * n256] = f; tab256[2 * n256 + 1] = off + 256 * j; ++n256;
      }
      for (int j = 0; j < (pc >> 7); ++j) {
        tab128[2 * n128] = f; tab128[2 * n128 + 1] = off + 128 * j; ++n128;
      }
      off += pc;
    }
    for (; n256 < MT256; ++n256) { tab256[2 * n256] = -1; tab256[2 * n256 + 1] = 0; }
    for (; n128 < MT128; ++n128) { tab128[2 * n128] = -1; tab128[2 * n128 + 1] = 0; }
  }
  __syncthreads();
  int pos = offs[e];
  for (int i = 0; i < TT / 64; ++i) {
    const int t = i * 64 + lane;
    const int2 k2 = topk[t];
    const bool sel = (k2.x == e || k2.y == e);
    const unsigned long long m = __ballot(sel);
    if (sel) {
      const int p = pos + __popcll(m & ((1ull << lane) - 1ull));
      tok_list[p] = t;
      wt_list[p] = combine[(size_t)t * EE + e];
    }
    pos += __popcll(m);
  }
  const int pc = (cnt + 255) & ~255;  // pad slots: token 0, weight 0
  for (int s = cnt + lane; s < pc; s += 64) {
    tok_list[offs[e] + s] = 0;
    wt_list[offs[e] + s] = 0.f;
  }
}

// ---------------- gather x rows (f32 -> bf16) into contiguous padded buffer ----------------
__global__ __launch_bounds__(256) void gather_x(
    const float* __restrict__ x, const int* __restrict__ tok_list,
    const int* __restrict__ tab256, unsigned short* __restrict__ xg) {
  const int e = tab256[2 * blockIdx.x];
  if (e < 0) return;
  const int row0 = tab256[2 * blockIdx.x + 1] + blockIdx.y * 16;
  const int tid = threadIdx.x;
#pragma unroll
  for (int i = 0; i < 16; ++i) {
    const int row = row0 + i;
    const int tok = tok_list[row];
    const f32x4 v = *(const f32x4*)(x + (size_t)tok * DD + tid * 4);
    unsigned short b[4] = {f2bf(v[0]), f2bf(v[1]), f2bf(v[2]), f2bf(v[3])};
    *(short4v*)(xg + (size_t)row * DD + tid * 4) = *(const short4v*)b;
  }
}

// ---------------- grouped GEMM: ring-3 K-tile slots, 2-phase/K-tile schedule ----------------
// MODE 0: BM=256 BN=256, A=xg [row][DD], B=wguT interleaved; epilogue silu(g)*u -> act bf16
// MODE 1: BM=128 BN=256, A=act [row][HH], B=wdT; epilogue atomic scatter * combine wt
// LDS swizzle: physical 16B-chunk = logical ^ ((row>>1)&3)  (rows are 64B at BK=32)
template <int MODE>
__global__ __launch_bounds__(512, 2) void gemm_main(
    const unsigned short* __restrict__ Ab, const unsigned short* __restrict__ Bb,
    const int* __restrict__ tab, const int* __restrict__ tok_list,
    const float* __restrict__ wt_list, unsigned short* __restrict__ act,
    float* __restrict__ out) {
  constexpr int K      = (MODE == 0) ? DD : HH;
  constexpr int BM     = (MODE == 0) ? 256 : 128;
  constexpr int NBR    = (MODE == 0) ? 2 * HH : DD;        // B rows per expert
  constexpr int NK     = K / 32;                           // 32 / 56 K-tiles
  constexpr int ABYTES = BM * 64;                          // A bytes per slot
  constexpr int SLOTB  = (BM + 256) * 64;                  // 32KB / 24KB
  constexpr int GLL    = SLOTB / 8192;                     // 4 / 3 gll per thread per tile
  constexpr int VCNT   = GLL;                              // counted vmcnt (next-next in flight)
  constexpr int NIT    = ((MODE == 0) ? 128 : 64) / 16;    // 8 / 4 acc rows
  constexpr int NNT    = NBR / 256;                        // 14 / 4 n-tiles
  extern __shared__ char lds[];

  // flattened grid, nt-fastest; XCD-chunk swizzle (grid % 8 == 0 for both modes)
  const int nwg = gridDim.x;
  const int wgid = (blockIdx.x & 7) * (nwg >> 3) + (blockIdx.x >> 3);
  const int mt = wgid / NNT, nt = wgid % NNT;
  const int e = tab[2 * mt];
  if (e < 0) return;
  const int row0 = tab[2 * mt + 1];
  const int n0 = nt * 256;

  const int tid = threadIdx.x, lane = tid & 63, wave = tid >> 6;
  const int wm = (wave >> 2) * ((MODE == 0) ? 128 : 64);
  const int wn = (wave & 3) * 64;
  const int fr = lane & 15, hi = lane >> 4;

  const unsigned short* At = Ab + (size_t)row0 * K;
  const unsigned short* Bt = Bb + ((size_t)e * NBR + n0) * K;

  asm volatile("s_waitcnt vmcnt(0)" ::: "memory");  // exact vmem accounting below

  // stage 16B-granule q of K-tile u into ring slot; LDS linear, source pre-swizzled
  auto stage_q = [&](int u, int slot, int q) {
    const int rel = q * 8192 + wave * 1024 + lane * 16;  // byte within slot
    const bool isA = rel < ABYTES;                       // uniform per (q,wave)
    const int rb = isA ? rel : rel - ABYTES;
    const int row = rb >> 6;                             // 64B rows
    const int l = (((rb >> 4) & 3)) ^ ((row >> 1) & 3);  // logical chunk
    gll16((isA ? At : Bt) + (size_t)row * K + u * 32 + l * 8,
          lds + slot * SLOTB + q * 8192 + wave * 1024);
  };
  auto rdA = [&](int slot, int m) -> short8 {
    const int c = hi ^ ((m >> 1) & 3);
    return *(const short8*)(lds + slot * SLOTB + m * 64 + (c << 4));
  };
  auto rdB = [&](int slot, int n) -> short8 {
    const int c = hi ^ ((n >> 1) & 3);
    return *(const short8*)(lds + slot * SLOTB + ABYTES + n * 64 + (c << 4));
  };

  f32x4 acc[NIT][4];
#pragma unroll
  for (int i = 0; i < NIT; ++i)
#pragma unroll
    for (int j = 0; j < 4; ++j) acc[i][j] = (f32x4){0.f, 0.f, 0.f, 0.f};

  // prologue: stage tiles 0,1; wait tile 0 landed (tile 1's GLL still in flight)
#pragma unroll
  for (int q = 0; q < GLL; ++q) stage_q(0, 0, q);
#pragma unroll
  for (int q = 0; q < GLL; ++q) stage_q(1, 1, q);
  if constexpr (VCNT == 4) asm volatile("s_waitcnt vmcnt(4)" ::: "memory");
  else                     asm volatile("s_waitcnt vmcnt(3)" ::: "memory");
  __builtin_amdgcn_s_barrier();

  int slot = 0;
#pragma unroll 1
  for (int t = 0; t < NK; ++t) {
    const int nslot = (slot >= 1) ? slot - 1 : slot + 2;        // (t+2)%3
    const int u = (t + 2 >= NK) ? t + 2 - NK : t + 2;           // tail: dummy re-stage
    short8 b[4];
    if constexpr (MODE == 0) {
      // ---- P1: A rows wm..wm+63, all B ----
      short8 a[4];
#pragma unroll
      for (int i = 0; i < 4; ++i) a[i] = rdA(slot, wm + i * 16 + fr);
#pragma unroll
      for (int j = 0; j < 4; ++j) b[j] = rdB(slot, wn + j * 16 + fr);
      stage_q(u, nslot, 0); stage_q(u, nslot, 1);
      __builtin_amdgcn_s_barrier();
      asm volatile("s_waitcnt lgkmcnt(0)" ::: "memory");
      __builtin_amdgcn_sched_barrier(0);
      __builtin_amdgcn_s_setprio(1);
#pragma unroll
      for (int i = 0; i < 4; ++i)
#pragma unroll
        for (int j = 0; j < 4; ++j)
          acc[i][j] = __builtin_amdgcn_mfma_f32_16x16x32_bf16(a[i], b[j], acc[i][j], 0, 0, 0);
      __builtin_amdgcn_s_setprio(0);
      __builtin_amdgcn_s_barrier();
      // ---- P2: A rows wm+64.., B reg-reused; counted vmcnt publishes tile t+1 ----
#pragma unroll
      for (int i = 0; i < 4; ++i) a[i] = rdA(slot, wm + 64 + i * 16 + fr);
      stage_q(u, nslot, 2); stage_q(u, nslot, 3);
      asm volatile("s_waitcnt vmcnt(4)" ::: "memory");
      __builtin_amdgcn_s_barrier();
      asm volatile("s_waitcnt lgkmcnt(0)" ::: "memory");
      __builtin_amdgcn_sched_barrier(0);
      __builtin_amdgcn_s_setprio(1);
#pragma unroll
      for (int i = 0; i < 4; ++i)
#pragma unroll
        for (int j = 0; j < 4; ++j)
          acc[4 + i][j] = __builtin_amdgcn_mfma_f32_16x16x32_bf16(a[i], b[j], acc[4 + i][j], 0, 0, 0);
      __builtin_amdgcn_s_setprio(0);
      __builtin_amdgcn_s_barrier();
    } else {
      // ---- P1: all A, B cols wn..wn+31 ----
      short8 a[4];
#pragma unroll
      for (int i = 0; i < 4; ++i) a[i] = rdA(slot, wm + i * 16 + fr);
#pragma unroll
      for (int j = 0; j < 2; ++j) b[j] = rdB(slot, wn + j * 16 + fr);
      stage_q(u, nslot, 0); stage_q(u, nslot, 1);
      __builtin_amdgcn_s_barrier();
      asm volatile("s_waitcnt lgkmcnt(0)" ::: "memory");
      __builtin_amdgcn_sched_barrier(0);
      __builtin_amdgcn_s_setprio(1);
#pragma unroll
      for (int i = 0; i < 4; ++i)
#pragma unroll
        for (int j = 0; j < 2; ++j)
          acc[i][j] = __builtin_amdgcn_mfma_f32_16x16x32_bf16(a[i], b[j], acc[i][j], 0, 0, 0);
      __builtin_amdgcn_s_setprio(0);
      __builtin_amdgcn_s_barrier();
      // ---- P2: B cols wn+32.., A reg-reused ----
#pragma unroll
      for (int j = 0; j < 2; ++j) b[2 + j] = rdB(slot, wn + 32 + j * 16 + fr);
      stage_q(u, nslot, 2);
      asm volatile("s_waitcnt vmcnt(3)" ::: "memory");
      __builtin_amdgcn_s_barrier();
      asm volatile("s_waitcnt lgkmcnt(0)" ::: "memory");
      __builtin_amdgcn_sched_barrier(0);
      __builtin_amdgcn_s_setprio(1);
#pragma unroll
      for (int i = 0; i < 4; ++i)
#pragma unroll
        for (int j = 0; j < 2; ++j)
          acc[i][2 + j] = __builtin_amdgcn_mfma_f32_16x16x32_bf16(a[i], b[2 + j], acc[i][2 + j], 0, 0, 0);
      __builtin_amdgcn_s_setprio(0);
      __builtin_amdgcn_s_barrier();
    }
    slot = (slot >= 2) ? 0 : slot + 1;
  }
  asm volatile("s_waitcnt vmcnt(0)" ::: "memory");

  const int r4 = hi * 4;
  if constexpr (MODE == 0) {
#pragma unroll
    for (int i = 0; i < NIT; ++i)
#pragma unroll
      for (int r = 0; r < 4; ++r) {
        const int row = row0 + wm + i * 16 + r4 + r;
#pragma unroll
        for (int jj = 0; jj < 2; ++jj) {
          const float g = acc[i][2 * jj][r], u = acc[i][2 * jj + 1][r];
          const int nb = n0 + wn + jj * 32;
          const int h = ((nb >> 5) << 4) + fr;   // de-interleave to real H col
          act[(size_t)row * HH + h] = f2bf((g / (1.f + expf(-g))) * u);
        }
      }
  } else {
#pragma unroll
    for (int i = 0; i < NIT; ++i)
#pragma unroll
      for (int r = 0; r < 4; ++r) {
        const int rl = row0 + wm + i * 16 + r4 + r;
        const int tok = tok_list[rl];
        const float wt = wt_list[rl];
        if (wt != 0.f) {
#pragma unroll
          for (int j = 0; j < 4; ++j)
            unsafeAtomicAdd(&out[(size_t)tok * DD + n0 + wn + j * 16 + fr],
                            acc[i][j][r] * wt);
        }
      }
  }
}

extern "C" void kernel_launch(void* const* d_in, const int* in_sizes, int n_in,
                              void* d_out, int out_size, void* d_ws, size_t ws_size,
                              hipStream_t stream) {
  const float* x      = (const float*)d_in[0];
  const float* gw     = (const float*)d_in[1];
  const float* w_gate = (const float*)d_in[2];
  const float* w_up   = (const float*)d_in[3];
  const float* w_down = (const float*)d_in[4];
  float* out = (float*)d_out;
  float* tail = out + (size_t)TT * DD;  // [loss, mean_probs x 8]

  char* w = (char*)d_ws;
  size_t o = 0;
  auto carve = [&](size_t bytes) { char* p = w + o; o += (bytes + 255) & ~255ull; return p; };
  unsigned short* wguT = (unsigned short*)carve((size_t)EE * 2 * HH * DD * 2);  // interleaved G/U
  unsigned short* wdT  = (unsigned short*)carve((size_t)EE * DD * HH * 2);
  unsigned short* xg   = (unsigned short*)carve((size_t)MP * DD * 2);
  unsigned short* act  = (unsigned short*)carve((size_t)MP * HH * 2);
  float* combine = (float*)carve((size_t)TT * EE * 4);
  float* probs   = (float*)carve((size_t)TT * EE * 4);
  int2* topk     = (int2*)carve((size_t)TT * 8);
  int* tok_list  = (int*)carve((size_t)MP * 4);
  float* wt_list = (float*)carve((size_t)MP * 4);
  int* tab256    = (int*)carve((size_t)MT256 * 8);
  int* tab128    = (int*)carve((size_t)MT128 * 8);

  hipMemsetAsync(out, 0, (size_t)TT * DD * sizeof(float), stream);

  transpose_convert<<<dim3(DD / 64, HH / 64, EE), 256, 0, stream>>>(w_gate, wguT, DD, HH, 1, 0);
  transpose_convert<<<dim3(DD / 64, HH / 64, EE), 256, 0, stream>>>(w_up,   wguT, DD, HH, 1, 1);
  transpose_convert<<<dim3(HH / 64, DD / 64, EE), 256, 0, stream>>>(w_down, wdT,  HH, DD, 0, 0);

  gate_kernel<<<TT / 4, 256, 0, stream>>>(x, gw, combine, probs, topk);
  reduce_kernel<<<1, 256, 0, stream>>>(probs, tail);
  route_kernel<<<1, 512, 0, stream>>>(topk, combine, tok_list, wt_list, tab256, tab128);
  gather_x<<<dim3(MT256, 16), 256, 0, stream>>>(x, tok_list, tab256, xg);

  hipFuncSetAttribute(reinterpret_cast<const void*>(&gemm_main<0>),
                      hipFuncAttributeMaxDynamicSharedMemorySize, 98304);
  hipFuncSetAttribute(reinterpret_cast<const void*>(&gemm_main<1>),
                      hipFuncAttributeMaxDynamicSharedMemorySize, 73728);

  gemm_main<0><<<MT256 * 14, 512, 98304, stream>>>(xg, wguT, tab256, nullptr, nullptr, act, nullptr);
  gemm_main<1><<<MT128 * 4, 512, 73728, stream>>>(act, wdT, tab128, tok_list, wt_list, nullptr, out);
}